// Round 1
// baseline (1009.015 us; speedup 1.0000x reference)
//
#include <hip/hip_runtime.h>
#include <math.h>

#define BB 128
#define NN 256
#define EE 2048
#define BINS 16

// ---------------- degree / dinv ----------------
__global__ void deg_kernel(const int* __restrict__ ei, float* __restrict__ dinv) {
    int b = blockIdx.x;
    int t = threadIdx.x;
    __shared__ int cnt[NN];
    cnt[t] = 0;
    __syncthreads();
    const int* dst = ei + b * 2 * EE + EE;
    for (int e = t; e < EE; e += 256) atomicAdd(&cnt[dst[e]], 1);
    __syncthreads();
    dinv[b * NN + t] = rsqrtf((float)cnt[t] + 1.0f);
}

// ---------------- per-graph matmul: H[b] = X[b] @ W ----------------
// grid: BB * (NN/16), block 256
template<int FIN, int FOUT>
__global__ void mm_kernel(const float* __restrict__ X, const float* __restrict__ W,
                          float* __restrict__ H) {
    constexpr int RG = 256 / FOUT;   // row-groups concurrently
    constexpr int NR = 16 / RG;      // rows per thread
    int blk = blockIdx.x;
    int b = blk / (NN / 16);
    int rb = blk % (NN / 16);
    const float* x = X + ((size_t)b * NN + rb * 16) * FIN;
    float* h = H + ((size_t)b * NN + rb * 16) * FOUT;
    __shared__ float xs[16 * FIN];
    int t = threadIdx.x;
    for (int i = t; i < 16 * FIN; i += 256) xs[i] = x[i];
    __syncthreads();
    int c = t % FOUT;
    int r0 = t / FOUT;
    float acc[NR];
#pragma unroll
    for (int i = 0; i < NR; i++) acc[i] = 0.f;
    for (int k = 0; k < FIN; k++) {
        float w = W[k * FOUT + c];
#pragma unroll
        for (int i = 0; i < NR; i++) acc[i] += xs[(r0 + i * RG) * FIN + k] * w;
    }
#pragma unroll
    for (int i = 0; i < NR; i++) h[(r0 + i * RG) * FOUT + c] = acc[i];
}

// ---------------- GCN aggregate: OUT = scatter(h[src]*coef -> dst) + h/deg + b ----------------
// grid: BB * (FOUT/32), block 256. 32-channel chunk of the whole graph in LDS.
template<int FOUT, bool RELU>
__global__ void agg_kernel(const float* __restrict__ H, const int* __restrict__ ei,
                           const float* __restrict__ dinv, const float* __restrict__ bias,
                           float* __restrict__ OUT) {
    constexpr int NCH = FOUT / 32;
    int b = blockIdx.x / NCH;
    int cb = (blockIdx.x % NCH) * 32;
    __shared__ float lds[NN * 33];
    int t = threadIdx.x;
    for (int i = t; i < NN * 33; i += 256) lds[i] = 0.f;
    __syncthreads();
    const int* src = ei + b * 2 * EE;
    const int* dst = src + EE;
    const float* dv = dinv + b * NN;
    const float* h = H + (size_t)b * NN * FOUT;
    int ch = t & 31;
    for (int e = (t >> 5); e < EE; e += 8) {
        int s = src[e], d = dst[e];
        float coef = dv[s] * dv[d];
        float v = h[s * FOUT + cb + ch];
        atomicAdd(&lds[d * 33 + ch], v * coef);
    }
    __syncthreads();
    float* out = OUT + (size_t)b * NN * FOUT;
    for (int i = t; i < NN * 32; i += 256) {
        int n = i >> 5, c = i & 31;
        float di = dv[n];
        float val = lds[n * 33 + c] + h[n * FOUT + cb + c] * di * di + bias[cb + c];
        if (RELU) val = fmaxf(val, 0.f);
        out[n * FOUT + cb + c] = val;
    }
}

// ---------------- attention pooling: one block per graph ----------------
__global__ void attpool_kernel(const float* __restrict__ X, const float* __restrict__ Watt,
                               float* __restrict__ e) {
    int b = blockIdx.x;
    int t = threadIdx.x;
    __shared__ float xs[NN * 33];
    __shared__ float red[256];
    __shared__ float mean_s[32], ctx_s[32], sc[NN];
    const float* x = X + (size_t)b * NN * 32;
    for (int i = t; i < NN * 32; i += 256) { int n = i >> 5, c = i & 31; xs[n * 33 + c] = x[i]; }
    __syncthreads();
    { // mean over nodes per channel
        int c = t & 31, p = t >> 5;
        float s = 0.f;
        for (int n = p * 32; n < (p + 1) * 32; n++) s += xs[n * 33 + c];
        red[t] = s;
    }
    __syncthreads();
    if (t < 32) {
        float m = 0.f;
        for (int p = 0; p < 8; p++) m += red[p * 32 + t];
        mean_s[t] = m / (float)NN;
    }
    __syncthreads();
    if (t < 32) {
        float a = 0.f;
        for (int f = 0; f < 32; f++) a += mean_s[f] * Watt[t * 32 + f];
        ctx_s[t] = tanhf(a);
    }
    __syncthreads();
    { // per-node sigmoid score (NN == 256 == blockDim)
        float a = 0.f;
        for (int f = 0; f < 32; f++) a += xs[t * 33 + f] * ctx_s[f];
        sc[t] = 1.f / (1.f + expf(-a));
    }
    __syncthreads();
    { // weighted sum
        int c = t & 31, p = t >> 5;
        float s = 0.f;
        for (int n = p * 32; n < (p + 1) * 32; n++) s += xs[n * 33 + c] * sc[n];
        red[t] = s;
    }
    __syncthreads();
    if (t < 32) {
        float s = 0.f;
        for (int p = 0; p < 8; p++) s += red[p * 32 + t];
        e[b * 32 + t] = s;
    }
}

// ---------------- pairwise dots S[b,n,m] + per-block min/max ----------------
// grid: BB*4*4 (64x64 tiles), block 256
__global__ void pairdot_kernel(const float* __restrict__ Q, const float* __restrict__ C,
                               float* __restrict__ S, float* __restrict__ bmin,
                               float* __restrict__ bmax) {
    int blk = blockIdx.x;
    int b = blk / 16;
    int tn = (blk % 16) >> 2, tm = blk & 3;
    __shared__ float qs[64 * 33], cs[64 * 33];
    int t = threadIdx.x;
    const float* q = Q + ((size_t)b * NN + tn * 64) * 32;
    const float* c = C + ((size_t)b * NN + tm * 64) * 32;
    for (int i = t; i < 64 * 32; i += 256) {
        int n = i >> 5, f = i & 31;
        qs[n * 33 + f] = q[i];
        cs[n * 33 + f] = c[i];
    }
    __syncthreads();
    int m = t & 63, n0 = t >> 6;  // 4 row-groups
    float acc[16];
#pragma unroll
    for (int i = 0; i < 16; i++) acc[i] = 0.f;
    for (int f = 0; f < 32; f++) {
        float cv = cs[m * 33 + f];
#pragma unroll
        for (int i = 0; i < 16; i++) acc[i] += qs[(n0 + 4 * i) * 33 + f] * cv;
    }
    float lmin = acc[0], lmax = acc[0];
    float* sp = S + ((size_t)b * NN + tn * 64) * NN + tm * 64;
#pragma unroll
    for (int i = 0; i < 16; i++) {
        sp[(n0 + 4 * i) * NN + m] = acc[i];
        lmin = fminf(lmin, acc[i]);
        lmax = fmaxf(lmax, acc[i]);
    }
    __shared__ float rmin[256], rmax[256];
    rmin[t] = lmin; rmax[t] = lmax;
    __syncthreads();
    for (int s = 128; s > 0; s >>= 1) {
        if (t < s) { rmin[t] = fminf(rmin[t], rmin[t + s]); rmax[t] = fmaxf(rmax[t], rmax[t + s]); }
        __syncthreads();
    }
    if (t == 0) { bmin[blk] = rmin[0]; bmax[blk] = rmax[0]; }
}

// ---------------- global min/max reduce (1 block) + zero counts ----------------
__global__ void minmax_kernel(const float* __restrict__ bmin, const float* __restrict__ bmax,
                              float* __restrict__ lohi, float* __restrict__ counts) {
    __shared__ float rmin[256], rmax[256];
    int t = threadIdx.x;
    float lmin = 1e30f, lmax = -1e30f;
    for (int i = t; i < 2048; i += 256) { lmin = fminf(lmin, bmin[i]); lmax = fmaxf(lmax, bmax[i]); }
    rmin[t] = lmin; rmax[t] = lmax;
    __syncthreads();
    for (int s = 128; s > 0; s >>= 1) {
        if (t < s) { rmin[t] = fminf(rmin[t], rmin[t + s]); rmax[t] = fmaxf(rmax[t], rmax[t + s]); }
        __syncthreads();
    }
    if (t == 0) { lohi[0] = rmin[0]; lohi[1] = rmax[0]; }
    if (t < BINS) counts[t] = 0.f;
}

// ---------------- histogram (ballot-based, no per-element atomics) ----------------
__global__ void hist_kernel(const float* __restrict__ S, const float* __restrict__ lohi,
                            float* __restrict__ counts) {
    int t = blockIdx.x * blockDim.x + threadIdx.x;
    int lane = threadIdx.x & 63;
    float lo = lohi[0], hi = lohi[1];
    float scale = (float)BINS / (hi - lo);
    int cnt = 0;
    const size_t total = (size_t)BB * NN * NN;
    for (size_t i = t; i < total; i += (size_t)gridDim.x * blockDim.x) {
        float s = S[i];
        int idx = (int)floorf((s - lo) * scale);
        idx = min(max(idx, 0), BINS - 1);
#pragma unroll
        for (int bn = 0; bn < BINS; bn++) {
            unsigned long long msk = __ballot(idx == bn);
            if (lane == bn) cnt += __popcll(msk);
        }
    }
    __shared__ float wbins[4][BINS];
    int wave = threadIdx.x >> 6;
    if (lane < BINS) wbins[wave][lane] = (float)cnt;
    __syncthreads();
    if (threadIdx.x < BINS) {
        float s = wbins[0][threadIdx.x] + wbins[1][threadIdx.x] +
                  wbins[2][threadIdx.x] + wbins[3][threadIdx.x];
        atomicAdd(&counts[threadIdx.x], s);
    }
}

// ---------------- NTN + histogram concat + fc1 + fc2 head ----------------
__global__ void final_kernel(const float* __restrict__ e1, const float* __restrict__ e2,
                             const float* __restrict__ ntnW, const float* __restrict__ ntnV,
                             const float* __restrict__ ntnb, const float* __restrict__ counts,
                             const float* __restrict__ fc1W, const float* __restrict__ fc1b,
                             const float* __restrict__ fc2W, const float* __restrict__ fc2b,
                             float* __restrict__ out) {
    int b = blockIdx.x;
    int t = threadIdx.x;  // 256
    __shared__ float a1[32], a2[32], red[256], z[32], u[16];
    if (t < 32) a1[t] = e1[b * 32 + t];
    else if (t < 64) a2[t - 32] = e2[b * 32 + t - 32];
    __syncthreads();
    // bilinear partials: tensor-slice tt, i-rows {g, g+16}
    int tt = t >> 4, g = t & 15;
    float p = 0.f;
#pragma unroll
    for (int ii = 0; ii < 2; ii++) {
        int i = g + 16 * ii;
        float d = 0.f;
        const float* wr = ntnW + (tt * 32 + i) * 32;
        for (int j = 0; j < 32; j++) d += wr[j] * a2[j];
        p += a1[i] * d;
    }
    red[t] = p;
    __syncthreads();
    if (t < 16) {
        float s = 0.f;
        for (int g2 = 0; g2 < 16; g2++) s += red[t * 16 + g2];
        float lin = ntnb[t];
        for (int i = 0; i < 32; i++) lin += ntnV[t * 64 + i] * a1[i];
        for (int i = 0; i < 32; i++) lin += ntnV[t * 64 + 32 + i] * a2[i];
        z[t] = fmaxf(s + lin, 0.f);
    } else if (t < 32) {
        float tot = 0.f;
        for (int i = 0; i < BINS; i++) tot += counts[i];
        z[t] = counts[t - 16] / tot;
    }
    __syncthreads();
    if (t < 16) {
        float a = fc1b[t];
        for (int i = 0; i < 32; i++) a += fc1W[t * 32 + i] * z[i];
        u[t] = fmaxf(a, 0.f);
    }
    __syncthreads();
    if (t == 0) {
        float a = fc2b[0];
        for (int i = 0; i < 16; i++) a += fc2W[i] * u[i];
        out[b] = 1.f / (1.f + expf(-a));
    }
}

extern "C" void kernel_launch(void* const* d_in, const int* in_sizes, int n_in,
                              void* d_out, int out_size, void* d_ws, size_t ws_size,
                              hipStream_t stream) {
    const float* xq   = (const float*)d_in[0];
    const float* xc   = (const float*)d_in[1];
    const int*   eq   = (const int*)d_in[2];
    const int*   ec   = (const int*)d_in[3];
    const float* W1   = (const float*)d_in[4];
    const float* b1   = (const float*)d_in[5];
    const float* W2   = (const float*)d_in[6];
    const float* b2   = (const float*)d_in[7];
    const float* W3   = (const float*)d_in[8];
    const float* b3   = (const float*)d_in[9];
    const float* Watt = (const float*)d_in[10];
    const float* ntnW = (const float*)d_in[11];
    const float* ntnV = (const float*)d_in[12];
    const float* ntnb = (const float*)d_in[13];
    const float* fc1W = (const float*)d_in[14];
    const float* fc1b = (const float*)d_in[15];
    const float* fc2W = (const float*)d_in[16];
    const float* fc2b = (const float*)d_in[17];
    float* out = (float*)d_out;
    float* ws  = (float*)d_ws;

    // workspace layout (floats)
    float* dinvQ = ws;                         // 32768
    float* dinvC = dinvQ + 32768;              // 32768
    float* O3Q   = dinvC + 32768;              // 1048576
    float* O3C   = O3Q + 1048576;              // 1048576
    float* e1w   = O3C + 1048576;              // 4096
    float* e2w   = e1w + 4096;                 // 4096
    float* bmin  = e2w + 4096;                 // 2048
    float* bmax  = bmin + 2048;                // 2048
    float* lohi  = bmax + 2048;                // 2
    float* cntw  = lohi + 2;                   // 16
    float* big   = ws + 2175232;               // aligned big region
    float* Hbuf  = big;                        // 4194304 (matmul scratch, reused)
    float* O1Q   = big + 4194304;              // 4194304
    float* O2Q   = big + 8388608;              // 2097152
    float* O1C   = big + 10485760;             // 4194304
    float* O2C   = big + 14680064;             // 2097152
    float* Sbuf  = big;                        // 8388608, overlays Hbuf+O1Q (dead by then)

    deg_kernel<<<BB, 256, 0, stream>>>(eq, dinvQ);
    deg_kernel<<<BB, 256, 0, stream>>>(ec, dinvC);

    // side q
    mm_kernel<128, 128><<<BB * (NN / 16), 256, 0, stream>>>(xq, W1, Hbuf);
    agg_kernel<128, true><<<BB * 4, 256, 0, stream>>>(Hbuf, eq, dinvQ, b1, O1Q);
    mm_kernel<128, 64><<<BB * (NN / 16), 256, 0, stream>>>(O1Q, W2, Hbuf);
    agg_kernel<64, true><<<BB * 2, 256, 0, stream>>>(Hbuf, eq, dinvQ, b2, O2Q);
    mm_kernel<64, 32><<<BB * (NN / 16), 256, 0, stream>>>(O2Q, W3, Hbuf);
    agg_kernel<32, false><<<BB, 256, 0, stream>>>(Hbuf, eq, dinvQ, b3, O3Q);

    // side c
    mm_kernel<128, 128><<<BB * (NN / 16), 256, 0, stream>>>(xc, W1, Hbuf);
    agg_kernel<128, true><<<BB * 4, 256, 0, stream>>>(Hbuf, ec, dinvC, b1, O1C);
    mm_kernel<128, 64><<<BB * (NN / 16), 256, 0, stream>>>(O1C, W2, Hbuf);
    agg_kernel<64, true><<<BB * 2, 256, 0, stream>>>(Hbuf, ec, dinvC, b2, O2C);
    mm_kernel<64, 32><<<BB * (NN / 16), 256, 0, stream>>>(O2C, W3, Hbuf);
    agg_kernel<32, false><<<BB, 256, 0, stream>>>(Hbuf, ec, dinvC, b3, O3C);

    // pooling
    attpool_kernel<<<BB, 256, 0, stream>>>(O3Q, Watt, e1w);
    attpool_kernel<<<BB, 256, 0, stream>>>(O3C, Watt, e2w);

    // pairwise dot histogram
    pairdot_kernel<<<BB * 16, 256, 0, stream>>>(O3Q, O3C, Sbuf, bmin, bmax);
    minmax_kernel<<<1, 256, 0, stream>>>(bmin, bmax, lohi, cntw);
    hist_kernel<<<2048, 256, 0, stream>>>(Sbuf, lohi, cntw);

    // head
    final_kernel<<<BB, 256, 0, stream>>>(e1w, e2w, ntnW, ntnV, ntnb, cntw,
                                         fc1W, fc1b, fc2W, fc2b, out);
}

// Round 2
// 598.773 us; speedup vs baseline: 1.6851x; 1.6851x over previous
//
#include <hip/hip_runtime.h>
#include <math.h>

#define BB 128
#define NN 256
#define EE 2048
#define BINS 16

// ---------------- CSR build (per graph): counts, dinv, offsets, sorted src+weight ----------------
__global__ void csr_kernel(const int* __restrict__ ei, float* __restrict__ dinv,
                           int* __restrict__ off, int* __restrict__ srcs,
                           float* __restrict__ wts) {
    int b = blockIdx.x;
    int t = threadIdx.x;  // 256
    __shared__ int cnt[NN];
    __shared__ int sa[NN], sb[NN];
    __shared__ int cursor[NN];
    __shared__ float dvs[NN];
    cnt[t] = 0;
    __syncthreads();
    const int* src = ei + b * 2 * EE;
    const int* dst = src + EE;
    for (int e = t; e < EE; e += 256) atomicAdd(&cnt[dst[e]], 1);
    __syncthreads();
    float dv = rsqrtf((float)cnt[t] + 1.0f);
    dvs[t] = dv;
    dinv[b * NN + t] = dv;
    // inclusive scan of cnt
    sa[t] = cnt[t];
    __syncthreads();
    int* pin = sa; int* pout = sb;
    for (int d = 1; d < NN; d <<= 1) {
        int v = pin[t];
        if (t >= d) v += pin[t - d];
        pout[t] = v;
        __syncthreads();
        int* tmp = pin; pin = pout; pout = tmp;
    }
    int excl = pin[t] - cnt[t];
    off[b * 257 + t] = excl;
    if (t == 255) off[b * 257 + 256] = EE;
    cursor[t] = excl;
    __syncthreads();
    for (int e = t; e < EE; e += 256) {
        int d = dst[e], s = src[e];
        int pos = atomicAdd(&cursor[d], 1);
        srcs[b * EE + pos] = s;
        wts[b * EE + pos] = dvs[s] * dvs[d];
    }
}

// ---------------- per-graph matmul: H[b] = X[b] @ W ----------------
template<int FIN, int FOUT>
__global__ void mm_kernel(const float* __restrict__ X, const float* __restrict__ W,
                          float* __restrict__ H) {
    constexpr int RG = 256 / FOUT;
    constexpr int NR = 16 / RG;
    int blk = blockIdx.x;
    int b = blk / (NN / 16);
    int rb = blk % (NN / 16);
    const float* x = X + ((size_t)b * NN + rb * 16) * FIN;
    float* h = H + ((size_t)b * NN + rb * 16) * FOUT;
    __shared__ float xs[16 * FIN];
    int t = threadIdx.x;
    for (int i = t; i < 16 * FIN; i += 256) xs[i] = x[i];
    __syncthreads();
    int c = t % FOUT;
    int r0 = t / FOUT;
    float acc[NR];
#pragma unroll
    for (int i = 0; i < NR; i++) acc[i] = 0.f;
    for (int k = 0; k < FIN; k++) {
        float w = W[k * FOUT + c];
#pragma unroll
        for (int i = 0; i < NR; i++) acc[i] += xs[(r0 + i * RG) * FIN + k] * w;
    }
#pragma unroll
    for (int i = 0; i < NR; i++) h[(r0 + i * RG) * FOUT + c] = acc[i];
}

// ---------------- GCN aggregate via CSR gather (no atomics) ----------------
// grid: BB * (FOUT/32) * 4, block 256. Each block: graph b, 32-ch chunk, 64-node range.
template<int FOUT, bool RELU>
__global__ void aggr_kernel(const float* __restrict__ H, const int* __restrict__ off,
                            const int* __restrict__ srcs, const float* __restrict__ wts,
                            const float* __restrict__ dinv, const float* __restrict__ bias,
                            float* __restrict__ OUT) {
    constexpr int NCH = FOUT / 32;
    int blk = blockIdx.x;
    int b = blk / (NCH * 4);
    int rem = blk % (NCH * 4);
    int cb = (rem >> 2) * 32;
    int nb = (rem & 3) * 64;
    int t = threadIdx.x;
    int c = t & 31;
    const float* h = H + (size_t)b * NN * FOUT;
    const int* o = off + b * 257;
    const int* sr = srcs + b * EE;
    const float* w = wts + b * EE;
    const float* dv = dinv + b * NN;
    float* outp = OUT + (size_t)b * NN * FOUT;
    float bb = bias[cb + c];
    for (int n = nb + (t >> 5); n < nb + 64; n += 8) {
        int j0 = o[n], j1 = o[n + 1];
        float acc = 0.f;
        for (int j = j0; j < j1; j++) {
            acc += h[sr[j] * FOUT + cb + c] * w[j];
        }
        float d0 = dv[n];
        float val = acc + h[n * FOUT + cb + c] * d0 * d0 + bb;
        if (RELU) val = fmaxf(val, 0.f);
        outp[n * FOUT + cb + c] = val;
    }
}

// ---------------- attention pooling: one block per graph ----------------
__global__ void attpool_kernel(const float* __restrict__ X, const float* __restrict__ Watt,
                               float* __restrict__ e) {
    int b = blockIdx.x;
    int t = threadIdx.x;
    __shared__ float xs[NN * 33];
    __shared__ float red[256];
    __shared__ float mean_s[32], ctx_s[32], sc[NN];
    const float* x = X + (size_t)b * NN * 32;
    for (int i = t; i < NN * 32; i += 256) { int n = i >> 5, c = i & 31; xs[n * 33 + c] = x[i]; }
    __syncthreads();
    {
        int c = t & 31, p = t >> 5;
        float s = 0.f;
        for (int n = p * 32; n < (p + 1) * 32; n++) s += xs[n * 33 + c];
        red[t] = s;
    }
    __syncthreads();
    if (t < 32) {
        float m = 0.f;
        for (int p = 0; p < 8; p++) m += red[p * 32 + t];
        mean_s[t] = m / (float)NN;
    }
    __syncthreads();
    if (t < 32) {
        float a = 0.f;
        for (int f = 0; f < 32; f++) a += mean_s[f] * Watt[t * 32 + f];
        ctx_s[t] = tanhf(a);
    }
    __syncthreads();
    {
        float a = 0.f;
        for (int f = 0; f < 32; f++) a += xs[t * 33 + f] * ctx_s[f];
        sc[t] = 1.f / (1.f + expf(-a));
    }
    __syncthreads();
    {
        int c = t & 31, p = t >> 5;
        float s = 0.f;
        for (int n = p * 32; n < (p + 1) * 32; n++) s += xs[n * 33 + c] * sc[n];
        red[t] = s;
    }
    __syncthreads();
    if (t < 32) {
        float s = 0.f;
        for (int p = 0; p < 8; p++) s += red[p * 32 + t];
        e[b * 32 + t] = s;
    }
}

// ---------------- pairwise dots S[b,n,m] + per-block min/max ----------------
__global__ void pairdot_kernel(const float* __restrict__ Q, const float* __restrict__ C,
                               float* __restrict__ S, float* __restrict__ bmin,
                               float* __restrict__ bmax) {
    int blk = blockIdx.x;
    int b = blk / 16;
    int tn = (blk % 16) >> 2, tm = blk & 3;
    __shared__ float qs[64 * 33], cs[64 * 33];
    int t = threadIdx.x;
    const float* q = Q + ((size_t)b * NN + tn * 64) * 32;
    const float* c = C + ((size_t)b * NN + tm * 64) * 32;
    for (int i = t; i < 64 * 32; i += 256) {
        int n = i >> 5, f = i & 31;
        qs[n * 33 + f] = q[i];
        cs[n * 33 + f] = c[i];
    }
    __syncthreads();
    int m = t & 63, n0 = t >> 6;
    float acc[16];
#pragma unroll
    for (int i = 0; i < 16; i++) acc[i] = 0.f;
    for (int f = 0; f < 32; f++) {
        float cv = cs[m * 33 + f];
#pragma unroll
        for (int i = 0; i < 16; i++) acc[i] += qs[(n0 + 4 * i) * 33 + f] * cv;
    }
    float lmin = acc[0], lmax = acc[0];
    float* sp = S + ((size_t)b * NN + tn * 64) * NN + tm * 64;
#pragma unroll
    for (int i = 0; i < 16; i++) {
        sp[(n0 + 4 * i) * NN + m] = acc[i];
        lmin = fminf(lmin, acc[i]);
        lmax = fmaxf(lmax, acc[i]);
    }
    __shared__ float rmin[256], rmax[256];
    rmin[t] = lmin; rmax[t] = lmax;
    __syncthreads();
    for (int s = 128; s > 0; s >>= 1) {
        if (t < s) { rmin[t] = fminf(rmin[t], rmin[t + s]); rmax[t] = fmaxf(rmax[t], rmax[t + s]); }
        __syncthreads();
    }
    if (t == 0) { bmin[blk] = rmin[0]; bmax[blk] = rmax[0]; }
}

// ---------------- global min/max reduce (1 block) + zero counts ----------------
__global__ void minmax_kernel(const float* __restrict__ bmin, const float* __restrict__ bmax,
                              float* __restrict__ lohi, float* __restrict__ counts) {
    __shared__ float rmin[256], rmax[256];
    int t = threadIdx.x;
    float lmin = 1e30f, lmax = -1e30f;
    for (int i = t; i < 2048; i += 256) { lmin = fminf(lmin, bmin[i]); lmax = fmaxf(lmax, bmax[i]); }
    rmin[t] = lmin; rmax[t] = lmax;
    __syncthreads();
    for (int s = 128; s > 0; s >>= 1) {
        if (t < s) { rmin[t] = fminf(rmin[t], rmin[t + s]); rmax[t] = fmaxf(rmax[t], rmax[t + s]); }
        __syncthreads();
    }
    if (t == 0) { lohi[0] = rmin[0]; lohi[1] = rmax[0]; }
    if (t < BINS) counts[t] = 0.f;
}

// ---------------- histogram (ballot-based) ----------------
__global__ void hist_kernel(const float* __restrict__ S, const float* __restrict__ lohi,
                            float* __restrict__ counts) {
    int t = blockIdx.x * blockDim.x + threadIdx.x;
    int lane = threadIdx.x & 63;
    float lo = lohi[0], hi = lohi[1];
    float scale = (float)BINS / (hi - lo);
    int cnt = 0;
    const size_t total = (size_t)BB * NN * NN;
    for (size_t i = t; i < total; i += (size_t)gridDim.x * blockDim.x) {
        float s = S[i];
        int idx = (int)floorf((s - lo) * scale);
        idx = min(max(idx, 0), BINS - 1);
#pragma unroll
        for (int bn = 0; bn < BINS; bn++) {
            unsigned long long msk = __ballot(idx == bn);
            if (lane == bn) cnt += __popcll(msk);
        }
    }
    __shared__ float wbins[4][BINS];
    int wave = threadIdx.x >> 6;
    if (lane < BINS) wbins[wave][lane] = (float)cnt;
    __syncthreads();
    if (threadIdx.x < BINS) {
        float s = wbins[0][threadIdx.x] + wbins[1][threadIdx.x] +
                  wbins[2][threadIdx.x] + wbins[3][threadIdx.x];
        atomicAdd(&counts[threadIdx.x], s);
    }
}

// ---------------- NTN + histogram concat + fc1 + fc2 head ----------------
__global__ void final_kernel(const float* __restrict__ e1, const float* __restrict__ e2,
                             const float* __restrict__ ntnW, const float* __restrict__ ntnV,
                             const float* __restrict__ ntnb, const float* __restrict__ counts,
                             const float* __restrict__ fc1W, const float* __restrict__ fc1b,
                             const float* __restrict__ fc2W, const float* __restrict__ fc2b,
                             float* __restrict__ out) {
    int b = blockIdx.x;
    int t = threadIdx.x;
    __shared__ float a1[32], a2[32], red[256], z[32], u[16];
    if (t < 32) a1[t] = e1[b * 32 + t];
    else if (t < 64) a2[t - 32] = e2[b * 32 + t - 32];
    __syncthreads();
    int tt = t >> 4, g = t & 15;
    float p = 0.f;
#pragma unroll
    for (int ii = 0; ii < 2; ii++) {
        int i = g + 16 * ii;
        float d = 0.f;
        const float* wr = ntnW + (tt * 32 + i) * 32;
        for (int j = 0; j < 32; j++) d += wr[j] * a2[j];
        p += a1[i] * d;
    }
    red[t] = p;
    __syncthreads();
    if (t < 16) {
        float s = 0.f;
        for (int g2 = 0; g2 < 16; g2++) s += red[t * 16 + g2];
        float lin = ntnb[t];
        for (int i = 0; i < 32; i++) lin += ntnV[t * 64 + i] * a1[i];
        for (int i = 0; i < 32; i++) lin += ntnV[t * 64 + 32 + i] * a2[i];
        z[t] = fmaxf(s + lin, 0.f);
    } else if (t < 32) {
        float tot = 0.f;
        for (int i = 0; i < BINS; i++) tot += counts[i];
        z[t] = counts[t - 16] / tot;
    }
    __syncthreads();
    if (t < 16) {
        float a = fc1b[t];
        for (int i = 0; i < 32; i++) a += fc1W[t * 32 + i] * z[i];
        u[t] = fmaxf(a, 0.f);
    }
    __syncthreads();
    if (t == 0) {
        float a = fc2b[0];
        for (int i = 0; i < 16; i++) a += fc2W[i] * u[i];
        out[b] = 1.f / (1.f + expf(-a));
    }
}

extern "C" void kernel_launch(void* const* d_in, const int* in_sizes, int n_in,
                              void* d_out, int out_size, void* d_ws, size_t ws_size,
                              hipStream_t stream) {
    const float* xq   = (const float*)d_in[0];
    const float* xc   = (const float*)d_in[1];
    const int*   eq   = (const int*)d_in[2];
    const int*   ec   = (const int*)d_in[3];
    const float* W1   = (const float*)d_in[4];
    const float* b1   = (const float*)d_in[5];
    const float* W2   = (const float*)d_in[6];
    const float* b2   = (const float*)d_in[7];
    const float* W3   = (const float*)d_in[8];
    const float* b3   = (const float*)d_in[9];
    const float* Watt = (const float*)d_in[10];
    const float* ntnW = (const float*)d_in[11];
    const float* ntnV = (const float*)d_in[12];
    const float* ntnb = (const float*)d_in[13];
    const float* fc1W = (const float*)d_in[14];
    const float* fc1b = (const float*)d_in[15];
    const float* fc2W = (const float*)d_in[16];
    const float* fc2b = (const float*)d_in[17];
    float* out = (float*)d_out;
    float* ws  = (float*)d_ws;

    // ---- workspace layout (float indices) ----
    float* dinvQ = ws;                          // 32768
    float* dinvC = dinvQ + 32768;               // 32768
    float* O3Q   = dinvC + 32768;               // 1048576
    float* O3C   = O3Q + 1048576;               // 1048576
    float* e1w   = O3C + 1048576;               // 4096
    float* e2w   = e1w + 4096;                  // 4096
    float* bmin  = e2w + 4096;                  // 2048
    float* bmax  = bmin + 2048;                 // 2048
    float* lohi  = bmax + 2048;                 // 2
    float* cntw  = lohi + 2;                    // 16
    int*   offQ  = (int*)(ws + 2175232);        // 128*257 = 32896
    int*   offC  = offQ + 32896;                // 32896
    int*   srcsQ = offC + 32896;                // 262144
    int*   srcsC = srcsQ + 262144;              // 262144
    float* wtsQ  = (float*)(srcsC + 262144);    // 262144
    float* wtsC  = wtsQ + 262144;               // 262144
    float* big   = ws + 3301376;
    float* Hbuf  = big;                         // 4194304
    float* O1    = big + 4194304;               // 4194304 (shared q/c)
    float* O2    = big + 8388608;               // 2097152 (shared q/c)
    float* Sbuf  = big;                         // 8388608, overlays Hbuf+O1 (dead by then)

    csr_kernel<<<BB, 256, 0, stream>>>(eq, dinvQ, offQ, srcsQ, wtsQ);
    csr_kernel<<<BB, 256, 0, stream>>>(ec, dinvC, offC, srcsC, wtsC);

    // side q
    mm_kernel<128, 128><<<BB * (NN / 16), 256, 0, stream>>>(xq, W1, Hbuf);
    aggr_kernel<128, true><<<BB * 4 * 4, 256, 0, stream>>>(Hbuf, offQ, srcsQ, wtsQ, dinvQ, b1, O1);
    mm_kernel<128, 64><<<BB * (NN / 16), 256, 0, stream>>>(O1, W2, Hbuf);
    aggr_kernel<64, true><<<BB * 2 * 4, 256, 0, stream>>>(Hbuf, offQ, srcsQ, wtsQ, dinvQ, b2, O2);
    mm_kernel<64, 32><<<BB * (NN / 16), 256, 0, stream>>>(O2, W3, Hbuf);
    aggr_kernel<32, false><<<BB * 1 * 4, 256, 0, stream>>>(Hbuf, offQ, srcsQ, wtsQ, dinvQ, b3, O3Q);

    // side c (reuses O1/O2)
    mm_kernel<128, 128><<<BB * (NN / 16), 256, 0, stream>>>(xc, W1, Hbuf);
    aggr_kernel<128, true><<<BB * 4 * 4, 256, 0, stream>>>(Hbuf, offC, srcsC, wtsC, dinvC, b1, O1);
    mm_kernel<128, 64><<<BB * (NN / 16), 256, 0, stream>>>(O1, W2, Hbuf);
    aggr_kernel<64, true><<<BB * 2 * 4, 256, 0, stream>>>(Hbuf, offC, srcsC, wtsC, dinvC, b2, O2);
    mm_kernel<64, 32><<<BB * (NN / 16), 256, 0, stream>>>(O2, W3, Hbuf);
    aggr_kernel<32, false><<<BB * 1 * 4, 256, 0, stream>>>(Hbuf, offC, srcsC, wtsC, dinvC, b3, O3C);

    // pooling
    attpool_kernel<<<BB, 256, 0, stream>>>(O3Q, Watt, e1w);
    attpool_kernel<<<BB, 256, 0, stream>>>(O3C, Watt, e2w);

    // pairwise dot histogram
    pairdot_kernel<<<BB * 16, 256, 0, stream>>>(O3Q, O3C, Sbuf, bmin, bmax);
    minmax_kernel<<<1, 256, 0, stream>>>(bmin, bmax, lohi, cntw);
    hist_kernel<<<2048, 256, 0, stream>>>(Sbuf, lohi, cntw);

    // head
    final_kernel<<<BB, 256, 0, stream>>>(e1w, e2w, ntnW, ntnV, ntnb, cntw,
                                         fc1W, fc1b, fc2W, fc2b, out);
}

// Round 3
// 441.169 us; speedup vs baseline: 2.2871x; 1.3572x over previous
//
#include <hip/hip_runtime.h>
#include <math.h>

#define BB 128
#define NN 256
#define EE 2048
#define BINS 16

// ---------------- CSR build (per graph): counts, dinv, offsets, sorted src+weight ----------------
__global__ void csr_kernel(const int* __restrict__ ei, float* __restrict__ dinv,
                           int* __restrict__ off, int* __restrict__ srcs,
                           float* __restrict__ wts) {
    int b = blockIdx.x;
    int t = threadIdx.x;  // 256
    __shared__ int cnt[NN];
    __shared__ int sa[NN], sb[NN];
    __shared__ int cursor[NN];
    __shared__ float dvs[NN];
    cnt[t] = 0;
    __syncthreads();
    const int* src = ei + b * 2 * EE;
    const int* dst = src + EE;
    for (int e = t; e < EE; e += 256) atomicAdd(&cnt[dst[e]], 1);
    __syncthreads();
    float dv = rsqrtf((float)cnt[t] + 1.0f);
    dvs[t] = dv;
    dinv[b * NN + t] = dv;
    sa[t] = cnt[t];
    __syncthreads();
    int* pin = sa; int* pout = sb;
    for (int d = 1; d < NN; d <<= 1) {
        int v = pin[t];
        if (t >= d) v += pin[t - d];
        pout[t] = v;
        __syncthreads();
        int* tmp = pin; pin = pout; pout = tmp;
    }
    int excl = pin[t] - cnt[t];
    off[b * 257 + t] = excl;
    if (t == 255) off[b * 257 + 256] = EE;
    cursor[t] = excl;
    __syncthreads();
    for (int e = t; e < EE; e += 256) {
        int d = dst[e], s = src[e];
        int pos = atomicAdd(&cursor[d], 1);
        srcs[b * EE + pos] = s;
        wts[b * EE + pos] = dvs[s] * dvs[d];
    }
}

// ---------------- fused GCN layer: H = X@W (LDS-resident) then CSR-gather aggregate ----------------
// grid: (FOUT/32) * BB, chunk-major (blocks of same graph are BB apart -> same XCD).
// block: 512 threads. LDS: hT 33.8K + xsT 16.6K + wt 2K = 52.4 KB -> 2 blocks/CU.
template<int FIN, int FOUT, bool RELU>
__global__ __launch_bounds__(512) void gcn_fused(
        const float* __restrict__ X, const float* __restrict__ W,
        const float* __restrict__ bias, const int* __restrict__ off,
        const int* __restrict__ srcs, const float* __restrict__ wts,
        const float* __restrict__ dinv, float* __restrict__ OUT) {
    int blk = blockIdx.x;
    int b = blk % BB;
    int cb = (blk / BB) * 32;
    int t = threadIdx.x;

    __shared__ float hT[NN * 33];      // H chunk [n][c], stride 33 (gather conflict-free)
    __shared__ float xsT[16 * 260];    // X k-tile, k-major [k][n], stride 260 (16B-aligned rows)
    __shared__ float wt[16 * 32];      // W k-tile [k][c]

    const float* xg = X + (size_t)b * NN * FIN;
    int l = t & 63;        // lane -> node quad (rows 4l..4l+3)
    int wv = t >> 6;       // wave -> channel quad (cols 4wv..4wv+3)

    float acc[4][4];
#pragma unroll
    for (int i = 0; i < 4; i++)
#pragma unroll
        for (int j = 0; j < 4; j++) acc[i][j] = 0.f;

    // staging mapping: thread covers row n=t>>1, k-offsets qk..qk+7
    int sn = t >> 1, qk = (t & 1) * 8;

    for (int k0 = 0; k0 < FIN; k0 += 16) {
        const float* xr = xg + sn * FIN + k0 + qk;
        float4 v0 = *(const float4*)xr;
        float4 v1 = *(const float4*)(xr + 4);
        xsT[(qk + 0) * 260 + sn] = v0.x;
        xsT[(qk + 1) * 260 + sn] = v0.y;
        xsT[(qk + 2) * 260 + sn] = v0.z;
        xsT[(qk + 3) * 260 + sn] = v0.w;
        xsT[(qk + 4) * 260 + sn] = v1.x;
        xsT[(qk + 5) * 260 + sn] = v1.y;
        xsT[(qk + 6) * 260 + sn] = v1.z;
        xsT[(qk + 7) * 260 + sn] = v1.w;
        wt[t < 512 ? t : 0] = W[(k0 + (t >> 5)) * FOUT + cb + (t & 31)];
        __syncthreads();
#pragma unroll
        for (int k = 0; k < 16; k++) {
            float4 xv = *(const float4*)&xsT[k * 260 + 4 * l];
            float4 wvv = *(const float4*)&wt[k * 32 + 4 * wv];
            acc[0][0] += xv.x * wvv.x; acc[0][1] += xv.x * wvv.y;
            acc[0][2] += xv.x * wvv.z; acc[0][3] += xv.x * wvv.w;
            acc[1][0] += xv.y * wvv.x; acc[1][1] += xv.y * wvv.y;
            acc[1][2] += xv.y * wvv.z; acc[1][3] += xv.y * wvv.w;
            acc[2][0] += xv.z * wvv.x; acc[2][1] += xv.z * wvv.y;
            acc[2][2] += xv.z * wvv.z; acc[2][3] += xv.z * wvv.w;
            acc[3][0] += xv.w * wvv.x; acc[3][1] += xv.w * wvv.y;
            acc[3][2] += xv.w * wvv.z; acc[3][3] += xv.w * wvv.w;
        }
        __syncthreads();
    }
    // write H chunk to LDS
#pragma unroll
    for (int i = 0; i < 4; i++)
#pragma unroll
        for (int j = 0; j < 4; j++)
            hT[(4 * l + i) * 33 + 4 * wv + j] = acc[i][j];
    __syncthreads();

    // CSR-gather aggregation from LDS
    int c = t & 31, ng = t >> 5;
    const int* o = off + b * 257;
    const int* sr = srcs + b * EE;
    const float* wgt = wts + b * EE;
    const float* dvp = dinv + b * NN;
    float bb_ = bias[cb + c];
    float* outp = OUT + (size_t)b * NN * FOUT;
    for (int n = ng; n < NN; n += 16) {
        int j0 = o[n], j1 = o[n + 1];
        float a = 0.f;
        for (int j = j0; j < j1; j++) a += hT[sr[j] * 33 + c] * wgt[j];
        float d0 = dvp[n];
        float val = a + hT[n * 33 + c] * d0 * d0 + bb_;
        if (RELU) val = fmaxf(val, 0.f);
        outp[n * FOUT + cb + c] = val;
    }
}

// ---------------- attention pooling: one block per graph ----------------
__global__ void attpool_kernel(const float* __restrict__ X, const float* __restrict__ Watt,
                               float* __restrict__ e) {
    int b = blockIdx.x;
    int t = threadIdx.x;
    __shared__ float xs[NN * 33];
    __shared__ float red[256];
    __shared__ float mean_s[32], ctx_s[32], sc[NN];
    const float* x = X + (size_t)b * NN * 32;
    for (int i = t; i < NN * 32; i += 256) { int n = i >> 5, c = i & 31; xs[n * 33 + c] = x[i]; }
    __syncthreads();
    {
        int c = t & 31, p = t >> 5;
        float s = 0.f;
        for (int n = p * 32; n < (p + 1) * 32; n++) s += xs[n * 33 + c];
        red[t] = s;
    }
    __syncthreads();
    if (t < 32) {
        float m = 0.f;
        for (int p = 0; p < 8; p++) m += red[p * 32 + t];
        mean_s[t] = m / (float)NN;
    }
    __syncthreads();
    if (t < 32) {
        float a = 0.f;
        for (int f = 0; f < 32; f++) a += mean_s[f] * Watt[t * 32 + f];
        ctx_s[t] = tanhf(a);
    }
    __syncthreads();
    {
        float a = 0.f;
        for (int f = 0; f < 32; f++) a += xs[t * 33 + f] * ctx_s[f];
        sc[t] = 1.f / (1.f + expf(-a));
    }
    __syncthreads();
    {
        int c = t & 31, p = t >> 5;
        float s = 0.f;
        for (int n = p * 32; n < (p + 1) * 32; n++) s += xs[n * 33 + c] * sc[n];
        red[t] = s;
    }
    __syncthreads();
    if (t < 32) {
        float s = 0.f;
        for (int p = 0; p < 8; p++) s += red[p * 32 + t];
        e[b * 32 + t] = s;
    }
}

// ---------------- pairwise dots S[b,n,m] + per-block min/max ----------------
__global__ void pairdot_kernel(const float* __restrict__ Q, const float* __restrict__ C,
                               float* __restrict__ S, float* __restrict__ bmin,
                               float* __restrict__ bmax) {
    int blk = blockIdx.x;
    int b = blk / 16;
    int tn = (blk % 16) >> 2, tm = blk & 3;
    __shared__ float qs[64 * 33], cs[64 * 33];
    int t = threadIdx.x;
    const float* q = Q + ((size_t)b * NN + tn * 64) * 32;
    const float* c = C + ((size_t)b * NN + tm * 64) * 32;
    for (int i = t; i < 64 * 32; i += 256) {
        int n = i >> 5, f = i & 31;
        qs[n * 33 + f] = q[i];
        cs[n * 33 + f] = c[i];
    }
    __syncthreads();
    int m = t & 63, n0 = t >> 6;
    float acc[16];
#pragma unroll
    for (int i = 0; i < 16; i++) acc[i] = 0.f;
    for (int f = 0; f < 32; f++) {
        float cv = cs[m * 33 + f];
#pragma unroll
        for (int i = 0; i < 16; i++) acc[i] += qs[(n0 + 4 * i) * 33 + f] * cv;
    }
    float lmin = acc[0], lmax = acc[0];
    float* sp = S + ((size_t)b * NN + tn * 64) * NN + tm * 64;
#pragma unroll
    for (int i = 0; i < 16; i++) {
        sp[(n0 + 4 * i) * NN + m] = acc[i];
        lmin = fminf(lmin, acc[i]);
        lmax = fmaxf(lmax, acc[i]);
    }
    __shared__ float rmin[256], rmax[256];
    rmin[t] = lmin; rmax[t] = lmax;
    __syncthreads();
    for (int s = 128; s > 0; s >>= 1) {
        if (t < s) { rmin[t] = fminf(rmin[t], rmin[t + s]); rmax[t] = fmaxf(rmax[t], rmax[t + s]); }
        __syncthreads();
    }
    if (t == 0) { bmin[blk] = rmin[0]; bmax[blk] = rmax[0]; }
}

// ---------------- global min/max reduce (1 block) + zero counts ----------------
__global__ void minmax_kernel(const float* __restrict__ bmin, const float* __restrict__ bmax,
                              float* __restrict__ lohi, float* __restrict__ counts) {
    __shared__ float rmin[256], rmax[256];
    int t = threadIdx.x;
    float lmin = 1e30f, lmax = -1e30f;
    for (int i = t; i < 2048; i += 256) { lmin = fminf(lmin, bmin[i]); lmax = fmaxf(lmax, bmax[i]); }
    rmin[t] = lmin; rmax[t] = lmax;
    __syncthreads();
    for (int s = 128; s > 0; s >>= 1) {
        if (t < s) { rmin[t] = fminf(rmin[t], rmin[t + s]); rmax[t] = fmaxf(rmax[t], rmax[t + s]); }
        __syncthreads();
    }
    if (t == 0) { lohi[0] = rmin[0]; lohi[1] = rmax[0]; }
    if (t < BINS) counts[t] = 0.f;
}

// ---------------- histogram (ballot-based) ----------------
__global__ void hist_kernel(const float* __restrict__ S, const float* __restrict__ lohi,
                            float* __restrict__ counts) {
    int t = blockIdx.x * blockDim.x + threadIdx.x;
    int lane = threadIdx.x & 63;
    float lo = lohi[0], hi = lohi[1];
    float scale = (float)BINS / (hi - lo);
    int cnt = 0;
    const size_t total = (size_t)BB * NN * NN;
    for (size_t i = t; i < total; i += (size_t)gridDim.x * blockDim.x) {
        float s = S[i];
        int idx = (int)floorf((s - lo) * scale);
        idx = min(max(idx, 0), BINS - 1);
#pragma unroll
        for (int bn = 0; bn < BINS; bn++) {
            unsigned long long msk = __ballot(idx == bn);
            if (lane == bn) cnt += __popcll(msk);
        }
    }
    __shared__ float wbins[4][BINS];
    int wave = threadIdx.x >> 6;
    if (lane < BINS) wbins[wave][lane] = (float)cnt;
    __syncthreads();
    if (threadIdx.x < BINS) {
        float s = wbins[0][threadIdx.x] + wbins[1][threadIdx.x] +
                  wbins[2][threadIdx.x] + wbins[3][threadIdx.x];
        atomicAdd(&counts[threadIdx.x], s);
    }
}

// ---------------- NTN + histogram concat + fc1 + fc2 head ----------------
__global__ void final_kernel(const float* __restrict__ e1, const float* __restrict__ e2,
                             const float* __restrict__ ntnW, const float* __restrict__ ntnV,
                             const float* __restrict__ ntnb, const float* __restrict__ counts,
                             const float* __restrict__ fc1W, const float* __restrict__ fc1b,
                             const float* __restrict__ fc2W, const float* __restrict__ fc2b,
                             float* __restrict__ out) {
    int b = blockIdx.x;
    int t = threadIdx.x;
    __shared__ float a1[32], a2[32], red[256], z[32], u[16];
    if (t < 32) a1[t] = e1[b * 32 + t];
    else if (t < 64) a2[t - 32] = e2[b * 32 + t - 32];
    __syncthreads();
    int tt = t >> 4, g = t & 15;
    float p = 0.f;
#pragma unroll
    for (int ii = 0; ii < 2; ii++) {
        int i = g + 16 * ii;
        float d = 0.f;
        const float* wr = ntnW + (tt * 32 + i) * 32;
        for (int j = 0; j < 32; j++) d += wr[j] * a2[j];
        p += a1[i] * d;
    }
    red[t] = p;
    __syncthreads();
    if (t < 16) {
        float s = 0.f;
        for (int g2 = 0; g2 < 16; g2++) s += red[t * 16 + g2];
        float lin = ntnb[t];
        for (int i = 0; i < 32; i++) lin += ntnV[t * 64 + i] * a1[i];
        for (int i = 0; i < 32; i++) lin += ntnV[t * 64 + 32 + i] * a2[i];
        z[t] = fmaxf(s + lin, 0.f);
    } else if (t < 32) {
        float tot = 0.f;
        for (int i = 0; i < BINS; i++) tot += counts[i];
        z[t] = counts[t - 16] / tot;
    }
    __syncthreads();
    if (t < 16) {
        float a = fc1b[t];
        for (int i = 0; i < 32; i++) a += fc1W[t * 32 + i] * z[i];
        u[t] = fmaxf(a, 0.f);
    }
    __syncthreads();
    if (t == 0) {
        float a = fc2b[0];
        for (int i = 0; i < 16; i++) a += fc2W[i] * u[i];
        out[b] = 1.f / (1.f + expf(-a));
    }
}

extern "C" void kernel_launch(void* const* d_in, const int* in_sizes, int n_in,
                              void* d_out, int out_size, void* d_ws, size_t ws_size,
                              hipStream_t stream) {
    const float* xq   = (const float*)d_in[0];
    const float* xc   = (const float*)d_in[1];
    const int*   eq   = (const int*)d_in[2];
    const int*   ec   = (const int*)d_in[3];
    const float* W1   = (const float*)d_in[4];
    const float* b1   = (const float*)d_in[5];
    const float* W2   = (const float*)d_in[6];
    const float* b2   = (const float*)d_in[7];
    const float* W3   = (const float*)d_in[8];
    const float* b3   = (const float*)d_in[9];
    const float* Watt = (const float*)d_in[10];
    const float* ntnW = (const float*)d_in[11];
    const float* ntnV = (const float*)d_in[12];
    const float* ntnb = (const float*)d_in[13];
    const float* fc1W = (const float*)d_in[14];
    const float* fc1b = (const float*)d_in[15];
    const float* fc2W = (const float*)d_in[16];
    const float* fc2b = (const float*)d_in[17];
    float* out = (float*)d_out;
    float* ws  = (float*)d_ws;

    // ---- workspace layout (float indices) ----
    float* dinvQ = ws;                          // 32768
    float* dinvC = dinvQ + 32768;               // 32768
    float* O3Q   = dinvC + 32768;               // 1048576
    float* O3C   = O3Q + 1048576;               // 1048576
    float* e1w   = O3C + 1048576;               // 4096
    float* e2w   = e1w + 4096;                  // 4096
    float* bmin  = e2w + 4096;                  // 2048
    float* bmax  = bmin + 2048;                 // 2048
    float* lohi  = bmax + 2048;                 // 2
    float* cntw  = lohi + 2;                    // 16
    int*   offQ  = (int*)(ws + 2175232);        // 128*257 = 32896
    int*   offC  = offQ + 32896;                // 32896
    int*   srcsQ = offC + 32896;                // 262144
    int*   srcsC = srcsQ + 262144;              // 262144
    float* wtsQ  = (float*)(srcsC + 262144);    // 262144
    float* wtsC  = wtsQ + 262144;               // 262144
    float* big   = ws + 3301376;
    float* O1    = big;                         // 4194304 (shared q/c)
    float* O2    = big + 4194304;               // 2097152 (shared q/c)
    float* Sbuf  = big;                         // 8388608, overlays O1+O2 (dead by then)

    csr_kernel<<<BB, 256, 0, stream>>>(eq, dinvQ, offQ, srcsQ, wtsQ);
    csr_kernel<<<BB, 256, 0, stream>>>(ec, dinvC, offC, srcsC, wtsC);

    // side q
    gcn_fused<128, 128, true><<<4 * BB, 512, 0, stream>>>(xq, W1, b1, offQ, srcsQ, wtsQ, dinvQ, O1);
    gcn_fused<128, 64, true><<<2 * BB, 512, 0, stream>>>(O1, W2, b2, offQ, srcsQ, wtsQ, dinvQ, O2);
    gcn_fused<64, 32, false><<<1 * BB, 512, 0, stream>>>(O2, W3, b3, offQ, srcsQ, wtsQ, dinvQ, O3Q);

    // side c (reuses O1/O2)
    gcn_fused<128, 128, true><<<4 * BB, 512, 0, stream>>>(xc, W1, b1, offC, srcsC, wtsC, dinvC, O1);
    gcn_fused<128, 64, true><<<2 * BB, 512, 0, stream>>>(O1, W2, b2, offC, srcsC, wtsC, dinvC, O2);
    gcn_fused<64, 32, false><<<1 * BB, 512, 0, stream>>>(O2, W3, b3, offC, srcsC, wtsC, dinvC, O3C);

    // pooling
    attpool_kernel<<<BB, 256, 0, stream>>>(O3Q, Watt, e1w);
    attpool_kernel<<<BB, 256, 0, stream>>>(O3C, Watt, e2w);

    // pairwise dot histogram
    pairdot_kernel<<<BB * 16, 256, 0, stream>>>(O3Q, O3C, Sbuf, bmin, bmax);
    minmax_kernel<<<1, 256, 0, stream>>>(bmin, bmax, lohi, cntw);
    hist_kernel<<<2048, 256, 0, stream>>>(Sbuf, lohi, cntw);

    // head
    final_kernel<<<BB, 256, 0, stream>>>(e1w, e2w, ntnW, ntnV, ntnb, cntw,
                                         fc1W, fc1b, fc2W, fc2b, out);
}

// Round 4
// 365.474 us; speedup vs baseline: 2.7608x; 1.2071x over previous
//
#include <hip/hip_runtime.h>
#include <math.h>

#define BB 128
#define NN 256
#define EE 2048
#define BINS 16

// ---------------- CSR build (per graph): counts, offsets, sorted src+weight ----------------
__global__ void csr_kernel(const int* __restrict__ ei,
                           int* __restrict__ off, int* __restrict__ srcs,
                           float* __restrict__ wts) {
    int b = blockIdx.x;
    int t = threadIdx.x;  // 256
    __shared__ int cnt[NN];
    __shared__ int sa[NN], sb[NN];
    __shared__ int cursor[NN];
    __shared__ float dvs[NN];
    cnt[t] = 0;
    __syncthreads();
    const int* src = ei + b * 2 * EE;
    const int* dst = src + EE;
    for (int e = t; e < EE; e += 256) atomicAdd(&cnt[dst[e]], 1);
    __syncthreads();
    dvs[t] = rsqrtf((float)cnt[t] + 1.0f);
    sa[t] = cnt[t];
    __syncthreads();
    int* pin = sa; int* pout = sb;
    for (int d = 1; d < NN; d <<= 1) {
        int v = pin[t];
        if (t >= d) v += pin[t - d];
        pout[t] = v;
        __syncthreads();
        int* tmp = pin; pin = pout; pout = tmp;
    }
    int excl = pin[t] - cnt[t];
    off[b * 257 + t] = excl;
    if (t == 255) off[b * 257 + 256] = EE;
    cursor[t] = excl;
    __syncthreads();
    for (int e = t; e < EE; e += 256) {
        int d = dst[e], s = src[e];
        int pos = atomicAdd(&cursor[d], 1);
        srcs[b * EE + pos] = s;
        wts[b * EE + pos] = dvs[s] * dvs[d];
    }
}

// ---------------- fused GCN layer: H = X@W (LDS-resident) then LDS CSR-gather ----------------
// grid: (FOUT/32) * BB. block 512. LDS ~70 KB -> 2 blocks/CU.
template<int FIN, int FOUT, bool RELU>
__global__ __launch_bounds__(512) void gcn_fused(
        const float* __restrict__ X, const float* __restrict__ W,
        const float* __restrict__ bias, const int* __restrict__ off,
        const int* __restrict__ srcs, const float* __restrict__ wts,
        float* __restrict__ OUT) {
    int blk = blockIdx.x;
    int b = blk % BB;
    int cb = (blk / BB) * 32;
    int t = threadIdx.x;

    __shared__ float hT[NN * 33];      // H chunk [n][c], stride 33
    __shared__ float xsT[16 * 260];    // X k-tile, k-major [k][n]
    __shared__ float wt[16 * 32];      // W k-tile [k][c]
    __shared__ int   eoff[NN + 1];
    __shared__ int   esrc[EE];
    __shared__ float ewt[EE];

    const float* xg = X + (size_t)b * NN * FIN;
    const int* o = off + b * 257;
    const int* sr = srcs + b * EE;
    const float* wg = wts + b * EE;

    // stage edges + offsets (coalesced; completes during k-loop, needed after it)
    for (int i = t; i < EE; i += 512) { esrc[i] = sr[i]; ewt[i] = wg[i]; }
    for (int i = t; i <= NN; i += 512) eoff[i] = o[i];

    int l = t & 63;        // lane -> node quad (rows 4l..4l+3)
    int wv = t >> 6;       // wave -> channel quad (cols 4wv..4wv+3)

    float acc[4][4];
#pragma unroll
    for (int i = 0; i < 4; i++)
#pragma unroll
        for (int j = 0; j < 4; j++) acc[i][j] = 0.f;

    // staging mapping: thread covers row sn, k-offsets qk..qk+7
    int sn = t >> 1, qk = (t & 1) * 8;
    const float* xr = xg + sn * FIN + qk;
    float4 v0 = *(const float4*)xr;
    float4 v1 = *(const float4*)(xr + 4);
    float wreg = W[(t >> 5) * FOUT + cb + (t & 31)];

    for (int k0 = 0; k0 < FIN; k0 += 16) {
        xsT[(qk + 0) * 260 + sn] = v0.x;
        xsT[(qk + 1) * 260 + sn] = v0.y;
        xsT[(qk + 2) * 260 + sn] = v0.z;
        xsT[(qk + 3) * 260 + sn] = v0.w;
        xsT[(qk + 4) * 260 + sn] = v1.x;
        xsT[(qk + 5) * 260 + sn] = v1.y;
        xsT[(qk + 6) * 260 + sn] = v1.z;
        xsT[(qk + 7) * 260 + sn] = v1.w;
        wt[t] = wreg;
        __syncthreads();
        // prefetch next k-tile while FMAs run on current
        if (k0 + 16 < FIN) {
            xr += 16;
            v0 = *(const float4*)xr;
            v1 = *(const float4*)(xr + 4);
            wreg = W[(k0 + 16 + (t >> 5)) * FOUT + cb + (t & 31)];
        }
#pragma unroll
        for (int k = 0; k < 16; k++) {
            float4 xv = *(const float4*)&xsT[k * 260 + 4 * l];
            float4 wvv = *(const float4*)&wt[k * 32 + 4 * wv];
            acc[0][0] += xv.x * wvv.x; acc[0][1] += xv.x * wvv.y;
            acc[0][2] += xv.x * wvv.z; acc[0][3] += xv.x * wvv.w;
            acc[1][0] += xv.y * wvv.x; acc[1][1] += xv.y * wvv.y;
            acc[1][2] += xv.y * wvv.z; acc[1][3] += xv.y * wvv.w;
            acc[2][0] += xv.z * wvv.x; acc[2][1] += xv.z * wvv.y;
            acc[2][2] += xv.z * wvv.z; acc[2][3] += xv.z * wvv.w;
            acc[3][0] += xv.w * wvv.x; acc[3][1] += xv.w * wvv.y;
            acc[3][2] += xv.w * wvv.z; acc[3][3] += xv.w * wvv.w;
        }
        __syncthreads();
    }
#pragma unroll
    for (int i = 0; i < 4; i++)
#pragma unroll
        for (int j = 0; j < 4; j++)
            hT[(4 * l + i) * 33 + 4 * wv + j] = acc[i][j];
    __syncthreads();

    // CSR-gather aggregation: everything in LDS
    int c = t & 31, ng = t >> 5;
    float bb_ = bias[cb + c];
    float* outp = OUT + (size_t)b * NN * FOUT;
    for (int n = ng; n < NN; n += 16) {
        int j0 = eoff[n], j1 = eoff[n + 1];
        float a = 0.f;
        for (int j = j0; j < j1; j++) a += hT[esrc[j] * 33 + c] * ewt[j];
        float d0 = rsqrtf((float)(j1 - j0) + 1.0f);
        float val = a + hT[n * 33 + c] * d0 * d0 + bb_;
        if (RELU) val = fmaxf(val, 0.f);
        outp[n * FOUT + cb + c] = val;
    }
}

// ---------------- attention pooling: one block per graph ----------------
__global__ void attpool_kernel(const float* __restrict__ X, const float* __restrict__ Watt,
                               float* __restrict__ e) {
    int b = blockIdx.x;
    int t = threadIdx.x;
    __shared__ float xs[NN * 33];
    __shared__ float red[256];
    __shared__ float mean_s[32], ctx_s[32], sc[NN];
    const float* x = X + (size_t)b * NN * 32;
    for (int i = t; i < NN * 32; i += 256) { int n = i >> 5, c = i & 31; xs[n * 33 + c] = x[i]; }
    __syncthreads();
    {
        int c = t & 31, p = t >> 5;
        float s = 0.f;
        for (int n = p * 32; n < (p + 1) * 32; n++) s += xs[n * 33 + c];
        red[t] = s;
    }
    __syncthreads();
    if (t < 32) {
        float m = 0.f;
        for (int p = 0; p < 8; p++) m += red[p * 32 + t];
        mean_s[t] = m / (float)NN;
    }
    __syncthreads();
    if (t < 32) {
        float a = 0.f;
        for (int f = 0; f < 32; f++) a += mean_s[f] * Watt[t * 32 + f];
        ctx_s[t] = tanhf(a);
    }
    __syncthreads();
    {
        float a = 0.f;
        for (int f = 0; f < 32; f++) a += xs[t * 33 + f] * ctx_s[f];
        sc[t] = 1.f / (1.f + expf(-a));
    }
    __syncthreads();
    {
        int c = t & 31, p = t >> 5;
        float s = 0.f;
        for (int n = p * 32; n < (p + 1) * 32; n++) s += xs[n * 33 + c] * sc[n];
        red[t] = s;
    }
    __syncthreads();
    if (t < 32) {
        float s = 0.f;
        for (int p = 0; p < 8; p++) s += red[p * 32 + t];
        e[b * 32 + t] = s;
    }
}

// ---------------- pass 1: pairwise dot min/max (no store) ----------------
__global__ void pairdot_minmax(const float* __restrict__ Q, const float* __restrict__ C,
                               float* __restrict__ bmin, float* __restrict__ bmax) {
    int blk = blockIdx.x;
    int b = blk / 16;
    int tn = (blk % 16) >> 2, tm = blk & 3;
    __shared__ float qs[64 * 33], cs[64 * 33];
    int t = threadIdx.x;
    const float* q = Q + ((size_t)b * NN + tn * 64) * 32;
    const float* c = C + ((size_t)b * NN + tm * 64) * 32;
    for (int i = t; i < 64 * 32; i += 256) {
        int n = i >> 5, f = i & 31;
        qs[n * 33 + f] = q[i];
        cs[n * 33 + f] = c[i];
    }
    __syncthreads();
    int m = t & 63, n0 = t >> 6;
    float acc[16];
#pragma unroll
    for (int i = 0; i < 16; i++) acc[i] = 0.f;
    for (int f = 0; f < 32; f++) {
        float cv = cs[m * 33 + f];
#pragma unroll
        for (int i = 0; i < 16; i++) acc[i] += qs[(n0 + 4 * i) * 33 + f] * cv;
    }
    float lmin = acc[0], lmax = acc[0];
#pragma unroll
    for (int i = 1; i < 16; i++) {
        lmin = fminf(lmin, acc[i]);
        lmax = fmaxf(lmax, acc[i]);
    }
    __shared__ float rmin[256], rmax[256];
    rmin[t] = lmin; rmax[t] = lmax;
    __syncthreads();
    for (int s = 128; s > 0; s >>= 1) {
        if (t < s) { rmin[t] = fminf(rmin[t], rmin[t + s]); rmax[t] = fmaxf(rmax[t], rmax[t + s]); }
        __syncthreads();
    }
    if (t == 0) { bmin[blk] = rmin[0]; bmax[blk] = rmax[0]; }
}

// ---------------- global min/max reduce (1 block) + zero counts ----------------
__global__ void minmax_kernel(const float* __restrict__ bmin, const float* __restrict__ bmax,
                              float* __restrict__ lohi, float* __restrict__ counts) {
    __shared__ float rmin[256], rmax[256];
    int t = threadIdx.x;
    float lmin = 1e30f, lmax = -1e30f;
    for (int i = t; i < 2048; i += 256) { lmin = fminf(lmin, bmin[i]); lmax = fmaxf(lmax, bmax[i]); }
    rmin[t] = lmin; rmax[t] = lmax;
    __syncthreads();
    for (int s = 128; s > 0; s >>= 1) {
        if (t < s) { rmin[t] = fminf(rmin[t], rmin[t + s]); rmax[t] = fmaxf(rmax[t], rmax[t + s]); }
        __syncthreads();
    }
    if (t == 0) { lohi[0] = rmin[0]; lohi[1] = rmax[0]; }
    if (t < BINS) counts[t] = 0.f;
}

// ---------------- pass 2: recompute dots, LDS-atomic histogram ----------------
__global__ void pairdot_hist(const float* __restrict__ Q, const float* __restrict__ C,
                             const float* __restrict__ lohi, float* __restrict__ counts) {
    int blk = blockIdx.x;
    int b = blk / 16;
    int tn = (blk % 16) >> 2, tm = blk & 3;
    __shared__ float qs[64 * 33], cs[64 * 33];
    __shared__ int hloc[BINS];
    int t = threadIdx.x;
    if (t < BINS) hloc[t] = 0;
    const float* q = Q + ((size_t)b * NN + tn * 64) * 32;
    const float* c = C + ((size_t)b * NN + tm * 64) * 32;
    for (int i = t; i < 64 * 32; i += 256) {
        int n = i >> 5, f = i & 31;
        qs[n * 33 + f] = q[i];
        cs[n * 33 + f] = c[i];
    }
    __syncthreads();
    int m = t & 63, n0 = t >> 6;
    float acc[16];
#pragma unroll
    for (int i = 0; i < 16; i++) acc[i] = 0.f;
    for (int f = 0; f < 32; f++) {
        float cv = cs[m * 33 + f];
#pragma unroll
        for (int i = 0; i < 16; i++) acc[i] += qs[(n0 + 4 * i) * 33 + f] * cv;
    }
    float lo = lohi[0], hi = lohi[1];
    float scale = (float)BINS / (hi - lo);
#pragma unroll
    for (int i = 0; i < 16; i++) {
        int idx = (int)floorf((acc[i] - lo) * scale);
        idx = min(max(idx, 0), BINS - 1);
        atomicAdd(&hloc[idx], 1);
    }
    __syncthreads();
    if (t < BINS) atomicAdd(&counts[t], (float)hloc[t]);
}

// ---------------- NTN + histogram concat + fc1 + fc2 head ----------------
__global__ void final_kernel(const float* __restrict__ e1, const float* __restrict__ e2,
                             const float* __restrict__ ntnW, const float* __restrict__ ntnV,
                             const float* __restrict__ ntnb, const float* __restrict__ counts,
                             const float* __restrict__ fc1W, const float* __restrict__ fc1b,
                             const float* __restrict__ fc2W, const float* __restrict__ fc2b,
                             float* __restrict__ out) {
    int b = blockIdx.x;
    int t = threadIdx.x;
    __shared__ float a1[32], a2[32], red[256], z[32], u[16];
    if (t < 32) a1[t] = e1[b * 32 + t];
    else if (t < 64) a2[t - 32] = e2[b * 32 + t - 32];
    __syncthreads();
    int tt = t >> 4, g = t & 15;
    float p = 0.f;
#pragma unroll
    for (int ii = 0; ii < 2; ii++) {
        int i = g + 16 * ii;
        float d = 0.f;
        const float* wr = ntnW + (tt * 32 + i) * 32;
        for (int j = 0; j < 32; j++) d += wr[j] * a2[j];
        p += a1[i] * d;
    }
    red[t] = p;
    __syncthreads();
    if (t < 16) {
        float s = 0.f;
        for (int g2 = 0; g2 < 16; g2++) s += red[t * 16 + g2];
        float lin = ntnb[t];
        for (int i = 0; i < 32; i++) lin += ntnV[t * 64 + i] * a1[i];
        for (int i = 0; i < 32; i++) lin += ntnV[t * 64 + 32 + i] * a2[i];
        z[t] = fmaxf(s + lin, 0.f);
    } else if (t < 32) {
        float tot = 0.f;
        for (int i = 0; i < BINS; i++) tot += counts[i];
        z[t] = counts[t - 16] / tot;
    }
    __syncthreads();
    if (t < 16) {
        float a = fc1b[t];
        for (int i = 0; i < 32; i++) a += fc1W[t * 32 + i] * z[i];
        u[t] = fmaxf(a, 0.f);
    }
    __syncthreads();
    if (t == 0) {
        float a = fc2b[0];
        for (int i = 0; i < 16; i++) a += fc2W[i] * u[i];
        out[b] = 1.f / (1.f + expf(-a));
    }
}

extern "C" void kernel_launch(void* const* d_in, const int* in_sizes, int n_in,
                              void* d_out, int out_size, void* d_ws, size_t ws_size,
                              hipStream_t stream) {
    const float* xq   = (const float*)d_in[0];
    const float* xc   = (const float*)d_in[1];
    const int*   eq   = (const int*)d_in[2];
    const int*   ec   = (const int*)d_in[3];
    const float* W1   = (const float*)d_in[4];
    const float* b1   = (const float*)d_in[5];
    const float* W2   = (const float*)d_in[6];
    const float* b2   = (const float*)d_in[7];
    const float* W3   = (const float*)d_in[8];
    const float* b3   = (const float*)d_in[9];
    const float* Watt = (const float*)d_in[10];
    const float* ntnW = (const float*)d_in[11];
    const float* ntnV = (const float*)d_in[12];
    const float* ntnb = (const float*)d_in[13];
    const float* fc1W = (const float*)d_in[14];
    const float* fc1b = (const float*)d_in[15];
    const float* fc2W = (const float*)d_in[16];
    const float* fc2b = (const float*)d_in[17];
    float* out = (float*)d_out;
    float* ws  = (float*)d_ws;

    // ---- workspace layout (float indices) ----
    float* O3Q   = ws;                          // 1048576
    float* O3C   = O3Q + 1048576;               // 1048576
    float* e1w   = O3C + 1048576;               // 4096
    float* e2w   = e1w + 4096;                  // 4096
    float* bmin  = e2w + 4096;                  // 2048
    float* bmax  = bmin + 2048;                 // 2048
    float* lohi  = bmax + 2048;                 // 2
    float* cntw  = lohi + 2;                    // 16
    int*   offQ  = (int*)(ws + 2109696);        // 128*257 = 32896
    int*   offC  = offQ + 32896;                // 32896
    int*   srcsQ = offC + 32896;                // 262144
    int*   srcsC = srcsQ + 262144;              // 262144
    float* wtsQ  = (float*)(srcsC + 262144);    // 262144
    float* wtsC  = wtsQ + 262144;               // 262144
    float* big   = ws + 3301376;
    float* O1    = big;                         // 4194304 (shared q/c)
    float* O2    = big + 4194304;               // 2097152 (shared q/c)

    csr_kernel<<<BB, 256, 0, stream>>>(eq, offQ, srcsQ, wtsQ);
    csr_kernel<<<BB, 256, 0, stream>>>(ec, offC, srcsC, wtsC);

    // side q
    gcn_fused<128, 128, true><<<4 * BB, 512, 0, stream>>>(xq, W1, b1, offQ, srcsQ, wtsQ, O1);
    gcn_fused<128, 64, true><<<2 * BB, 512, 0, stream>>>(O1, W2, b2, offQ, srcsQ, wtsQ, O2);
    gcn_fused<64, 32, false><<<1 * BB, 512, 0, stream>>>(O2, W3, b3, offQ, srcsQ, wtsQ, O3Q);

    // side c (reuses O1/O2)
    gcn_fused<128, 128, true><<<4 * BB, 512, 0, stream>>>(xc, W1, b1, offC, srcsC, wtsC, O1);
    gcn_fused<128, 64, true><<<2 * BB, 512, 0, stream>>>(O1, W2, b2, offC, srcsC, wtsC, O2);
    gcn_fused<64, 32, false><<<1 * BB, 512, 0, stream>>>(O2, W3, b3, offC, srcsC, wtsC, O3C);

    // pooling
    attpool_kernel<<<BB, 256, 0, stream>>>(O3Q, Watt, e1w);
    attpool_kernel<<<BB, 256, 0, stream>>>(O3C, Watt, e2w);

    // pairwise dot histogram (two-pass recompute, no S materialization)
    pairdot_minmax<<<BB * 16, 256, 0, stream>>>(O3Q, O3C, bmin, bmax);
    minmax_kernel<<<1, 256, 0, stream>>>(bmin, bmax, lohi, cntw);
    pairdot_hist<<<BB * 16, 256, 0, stream>>>(O3Q, O3C, lohi, cntw);

    // head
    final_kernel<<<BB, 256, 0, stream>>>(e1w, e2w, ntnW, ntnV, ntnb, cntw,
                                         fc1W, fc1b, fc2W, fc2b, out);
}

// Round 5
// 310.301 us; speedup vs baseline: 3.2517x; 1.1778x over previous
//
#include <hip/hip_runtime.h>
#include <math.h>

#define BB 128
#define NN 256
#define EE 2048
#define BINS 16

// ---------------- CSR build, both sides: g in [0,2B) ----------------
__global__ void csr_kernel(const int* __restrict__ eq, const int* __restrict__ ec,
                           int* __restrict__ off, int* __restrict__ srcs,
                           float* __restrict__ wts) {
    int g = blockIdx.x;                 // 0..2B-1
    int b = g < BB ? g : g - BB;
    const int* ei = g < BB ? eq : ec;
    int t = threadIdx.x;  // 256
    __shared__ int cnt[NN];
    __shared__ int sa[NN], sb[NN];
    __shared__ int cursor[NN];
    __shared__ float dvs[NN];
    cnt[t] = 0;
    __syncthreads();
    const int* src = ei + b * 2 * EE;
    const int* dst = src + EE;
    for (int e = t; e < EE; e += 256) atomicAdd(&cnt[dst[e]], 1);
    __syncthreads();
    dvs[t] = rsqrtf((float)cnt[t] + 1.0f);
    sa[t] = cnt[t];
    __syncthreads();
    int* pin = sa; int* pout = sb;
    for (int d = 1; d < NN; d <<= 1) {
        int v = pin[t];
        if (t >= d) v += pin[t - d];
        pout[t] = v;
        __syncthreads();
        int* tmp = pin; pin = pout; pout = tmp;
    }
    int excl = pin[t] - cnt[t];
    off[g * 257 + t] = excl;
    if (t == 255) off[g * 257 + 256] = EE;
    cursor[t] = excl;
    __syncthreads();
    for (int e = t; e < EE; e += 256) {
        int d = dst[e], s = src[e];
        int pos = atomicAdd(&cursor[d], 1);
        srcs[g * EE + pos] = s;
        wts[g * EE + pos] = dvs[s] * dvs[d];
    }
}

// ---------------- fused GCN layer (both sides): H = X@W (LDS) then LDS CSR-gather ----------------
// grid: (FOUT/32) * 2B. block 512. LDS ~70 KB -> 2 blocks/CU.
template<int FIN, int FOUT, bool RELU>
__global__ __launch_bounds__(512) void gcn_fused(
        const float* __restrict__ X0, const float* __restrict__ X1,
        const float* __restrict__ W, const float* __restrict__ bias,
        const int* __restrict__ off, const int* __restrict__ srcs,
        const float* __restrict__ wts, float* __restrict__ OUT) {
    int blk = blockIdx.x;
    int g = blk % (2 * BB);
    int cb = (blk / (2 * BB)) * 32;
    int t = threadIdx.x;

    __shared__ float hT[NN * 33];      // H chunk [n][c], stride 33
    __shared__ float xsT[16 * 260];    // X k-tile, k-major [k][n]
    __shared__ float wt[16 * 32];      // W k-tile [k][c]
    __shared__ int   eoff[NN + 1];
    __shared__ int   esrc[EE];
    __shared__ float ewt[EE];

    const float* xg = (g < BB) ? (X0 + (size_t)g * NN * FIN)
                               : (X1 + (size_t)(g - BB) * NN * FIN);
    const int* o = off + g * 257;
    const int* sr = srcs + (size_t)g * EE;
    const float* wg = wts + (size_t)g * EE;

    // stage edges + offsets (coalesced; completes during k-loop)
    for (int i = t; i < EE; i += 512) { esrc[i] = sr[i]; ewt[i] = wg[i]; }
    for (int i = t; i <= NN; i += 512) eoff[i] = o[i];

    int l = t & 63;        // lane -> node quad (rows 4l..4l+3)
    int wv = t >> 6;       // wave -> channel quad (cols 4wv..4wv+3)

    float acc[4][4];
#pragma unroll
    for (int i = 0; i < 4; i++)
#pragma unroll
        for (int j = 0; j < 4; j++) acc[i][j] = 0.f;

    int sn = t >> 1, qk = (t & 1) * 8;
    const float* xr = xg + sn * FIN + qk;
    float4 v0 = *(const float4*)xr;
    float4 v1 = *(const float4*)(xr + 4);
    float wreg = W[(t >> 5) * FOUT + cb + (t & 31)];

    for (int k0 = 0; k0 < FIN; k0 += 16) {
        xsT[(qk + 0) * 260 + sn] = v0.x;
        xsT[(qk + 1) * 260 + sn] = v0.y;
        xsT[(qk + 2) * 260 + sn] = v0.z;
        xsT[(qk + 3) * 260 + sn] = v0.w;
        xsT[(qk + 4) * 260 + sn] = v1.x;
        xsT[(qk + 5) * 260 + sn] = v1.y;
        xsT[(qk + 6) * 260 + sn] = v1.z;
        xsT[(qk + 7) * 260 + sn] = v1.w;
        wt[t] = wreg;
        __syncthreads();
        if (k0 + 16 < FIN) {
            xr += 16;
            v0 = *(const float4*)xr;
            v1 = *(const float4*)(xr + 4);
            wreg = W[(k0 + 16 + (t >> 5)) * FOUT + cb + (t & 31)];
        }
#pragma unroll
        for (int k = 0; k < 16; k++) {
            float4 xv = *(const float4*)&xsT[k * 260 + 4 * l];
            float4 wvv = *(const float4*)&wt[k * 32 + 4 * wv];
            acc[0][0] += xv.x * wvv.x; acc[0][1] += xv.x * wvv.y;
            acc[0][2] += xv.x * wvv.z; acc[0][3] += xv.x * wvv.w;
            acc[1][0] += xv.y * wvv.x; acc[1][1] += xv.y * wvv.y;
            acc[1][2] += xv.y * wvv.z; acc[1][3] += xv.y * wvv.w;
            acc[2][0] += xv.z * wvv.x; acc[2][1] += xv.z * wvv.y;
            acc[2][2] += xv.z * wvv.z; acc[2][3] += xv.z * wvv.w;
            acc[3][0] += xv.w * wvv.x; acc[3][1] += xv.w * wvv.y;
            acc[3][2] += xv.w * wvv.z; acc[3][3] += xv.w * wvv.w;
        }
        __syncthreads();
    }
#pragma unroll
    for (int i = 0; i < 4; i++)
#pragma unroll
        for (int j = 0; j < 4; j++)
            hT[(4 * l + i) * 33 + 4 * wv + j] = acc[i][j];
    __syncthreads();

    // CSR-gather aggregation: everything in LDS
    int c = t & 31, ng = t >> 5;
    float bb_ = bias[cb + c];
    float* outp = OUT + (size_t)g * NN * FOUT;
    for (int n = ng; n < NN; n += 16) {
        int j0 = eoff[n], j1 = eoff[n + 1];
        float a = 0.f;
        for (int j = j0; j < j1; j++) a += hT[esrc[j] * 33 + c] * ewt[j];
        float d0 = rsqrtf((float)(j1 - j0) + 1.0f);
        float val = a + hT[n * 33 + c] * d0 * d0 + bb_;
        if (RELU) val = fmaxf(val, 0.f);
        outp[n * FOUT + cb + c] = val;
    }
}

// ---------------- attention pooling (both sides): one block per graph ----------------
__global__ void attpool_kernel(const float* __restrict__ X, const float* __restrict__ Watt,
                               float* __restrict__ e) {
    int g = blockIdx.x;   // 0..2B-1
    int t = threadIdx.x;
    __shared__ float xs[NN * 33];
    __shared__ float red[256];
    __shared__ float mean_s[32], ctx_s[32], sc[NN];
    const float* x = X + (size_t)g * NN * 32;
    for (int i = t; i < NN * 32; i += 256) { int n = i >> 5, c = i & 31; xs[n * 33 + c] = x[i]; }
    __syncthreads();
    {
        int c = t & 31, p = t >> 5;
        float s = 0.f;
        for (int n = p * 32; n < (p + 1) * 32; n++) s += xs[n * 33 + c];
        red[t] = s;
    }
    __syncthreads();
    if (t < 32) {
        float m = 0.f;
        for (int p = 0; p < 8; p++) m += red[p * 32 + t];
        mean_s[t] = m / (float)NN;
    }
    __syncthreads();
    if (t < 32) {
        float a = 0.f;
        for (int f = 0; f < 32; f++) a += mean_s[f] * Watt[t * 32 + f];
        ctx_s[t] = tanhf(a);
    }
    __syncthreads();
    {
        float a = 0.f;
        for (int f = 0; f < 32; f++) a += xs[t * 33 + f] * ctx_s[f];
        sc[t] = 1.f / (1.f + expf(-a));
    }
    __syncthreads();
    {
        int c = t & 31, p = t >> 5;
        float s = 0.f;
        for (int n = p * 32; n < (p + 1) * 32; n++) s += xs[n * 33 + c] * sc[n];
        red[t] = s;
    }
    __syncthreads();
    if (t < 32) {
        float s = 0.f;
        for (int p = 0; p < 8; p++) s += red[p * 32 + t];
        e[g * 32 + t] = s;
    }
}

// ---------------- pass 1: pairwise dot min/max (no store) ----------------
__global__ void pairdot_minmax(const float* __restrict__ Q, const float* __restrict__ C,
                               float* __restrict__ bmin, float* __restrict__ bmax) {
    int blk = blockIdx.x;
    int b = blk / 16;
    int tn = (blk % 16) >> 2, tm = blk & 3;
    __shared__ float qs[64 * 33], cs[64 * 33];
    int t = threadIdx.x;
    const float* q = Q + ((size_t)b * NN + tn * 64) * 32;
    const float* c = C + ((size_t)b * NN + tm * 64) * 32;
    for (int i = t; i < 64 * 32; i += 256) {
        int n = i >> 5, f = i & 31;
        qs[n * 33 + f] = q[i];
        cs[n * 33 + f] = c[i];
    }
    __syncthreads();
    int m = t & 63, n0 = t >> 6;
    float acc[16];
#pragma unroll
    for (int i = 0; i < 16; i++) acc[i] = 0.f;
    for (int f = 0; f < 32; f++) {
        float cv = cs[m * 33 + f];
#pragma unroll
        for (int i = 0; i < 16; i++) acc[i] += qs[(n0 + 4 * i) * 33 + f] * cv;
    }
    float lmin = acc[0], lmax = acc[0];
#pragma unroll
    for (int i = 1; i < 16; i++) {
        lmin = fminf(lmin, acc[i]);
        lmax = fmaxf(lmax, acc[i]);
    }
    __shared__ float rmin[256], rmax[256];
    rmin[t] = lmin; rmax[t] = lmax;
    __syncthreads();
    for (int s = 128; s > 0; s >>= 1) {
        if (t < s) { rmin[t] = fminf(rmin[t], rmin[t + s]); rmax[t] = fmaxf(rmax[t], rmax[t + s]); }
        __syncthreads();
    }
    if (t == 0) { bmin[blk] = rmin[0]; bmax[blk] = rmax[0]; }
}

// ---------------- global min/max reduce (1 block) + zero counts ----------------
__global__ void minmax_kernel(const float* __restrict__ bmin, const float* __restrict__ bmax,
                              float* __restrict__ lohi, float* __restrict__ counts) {
    __shared__ float rmin[256], rmax[256];
    int t = threadIdx.x;
    float lmin = 1e30f, lmax = -1e30f;
    for (int i = t; i < 2048; i += 256) { lmin = fminf(lmin, bmin[i]); lmax = fmaxf(lmax, bmax[i]); }
    rmin[t] = lmin; rmax[t] = lmax;
    __syncthreads();
    for (int s = 128; s > 0; s >>= 1) {
        if (t < s) { rmin[t] = fminf(rmin[t], rmin[t + s]); rmax[t] = fmaxf(rmax[t], rmax[t + s]); }
        __syncthreads();
    }
    if (t == 0) { lohi[0] = rmin[0]; lohi[1] = rmax[0]; }
    if (t < BINS) counts[t] = 0.f;
}

// ---------------- pass 2: recompute dots, bit-sliced ballot histogram (no LDS atomics) ----------------
__global__ void pairdot_hist(const float* __restrict__ Q, const float* __restrict__ C,
                             const float* __restrict__ lohi, float* __restrict__ counts) {
    int blk = blockIdx.x;
    int b = blk / 16;
    int tn = (blk % 16) >> 2, tm = blk & 3;
    __shared__ float qs[64 * 33], cs[64 * 33];
    int t = threadIdx.x;
    const float* q = Q + ((size_t)b * NN + tn * 64) * 32;
    const float* c = C + ((size_t)b * NN + tm * 64) * 32;
    for (int i = t; i < 64 * 32; i += 256) {
        int n = i >> 5, f = i & 31;
        qs[n * 33 + f] = q[i];
        cs[n * 33 + f] = c[i];
    }
    __syncthreads();
    int m = t & 63, n0 = t >> 6;
    float acc[16];
#pragma unroll
    for (int i = 0; i < 16; i++) acc[i] = 0.f;
    for (int f = 0; f < 32; f++) {
        float cv = cs[m * 33 + f];
#pragma unroll
        for (int i = 0; i < 16; i++) acc[i] += qs[(n0 + 4 * i) * 33 + f] * cv;
    }
    float lo = lohi[0], hi = lohi[1];
    float scale = (float)BINS / (hi - lo);
    int lane = t & 63;
    int cnt = 0;   // lane L accumulates count for bin (L & 15)
#pragma unroll
    for (int i = 0; i < 16; i++) {
        int idx = (int)floorf((acc[i] - lo) * scale);
        idx = min(max(idx, 0), BINS - 1);
        unsigned long long b0 = __ballot((idx & 1) != 0);
        unsigned long long b1 = __ballot((idx & 2) != 0);
        unsigned long long b2 = __ballot((idx & 4) != 0);
        unsigned long long b3 = __ballot((idx & 8) != 0);
        unsigned long long msk = ((lane & 1) ? b0 : ~b0);
        msk &= ((lane & 2) ? b1 : ~b1);
        msk &= ((lane & 4) ? b2 : ~b2);
        msk &= ((lane & 8) ? b3 : ~b3);
        cnt += __popcll(msk);
    }
    __shared__ float wbins[4][BINS];
    int wave = t >> 6;
    if (lane < BINS) wbins[wave][lane] = (float)cnt;
    __syncthreads();
    if (t < BINS) {
        atomicAdd(&counts[t], wbins[0][t] + wbins[1][t] + wbins[2][t] + wbins[3][t]);
    }
}

// ---------------- NTN + histogram concat + fc1 + fc2 head ----------------
__global__ void final_kernel(const float* __restrict__ e1, const float* __restrict__ e2,
                             const float* __restrict__ ntnW, const float* __restrict__ ntnV,
                             const float* __restrict__ ntnb, const float* __restrict__ counts,
                             const float* __restrict__ fc1W, const float* __restrict__ fc1b,
                             const float* __restrict__ fc2W, const float* __restrict__ fc2b,
                             float* __restrict__ out) {
    int b = blockIdx.x;
    int t = threadIdx.x;
    __shared__ float a1[32], a2[32], red[256], z[32], u[16];
    if (t < 32) a1[t] = e1[b * 32 + t];
    else if (t < 64) a2[t - 32] = e2[b * 32 + t - 32];
    __syncthreads();
    int tt = t >> 4, g = t & 15;
    float p = 0.f;
#pragma unroll
    for (int ii = 0; ii < 2; ii++) {
        int i = g + 16 * ii;
        float d = 0.f;
        const float* wr = ntnW + (tt * 32 + i) * 32;
        for (int j = 0; j < 32; j++) d += wr[j] * a2[j];
        p += a1[i] * d;
    }
    red[t] = p;
    __syncthreads();
    if (t < 16) {
        float s = 0.f;
        for (int g2 = 0; g2 < 16; g2++) s += red[t * 16 + g2];
        float lin = ntnb[t];
        for (int i = 0; i < 32; i++) lin += ntnV[t * 64 + i] * a1[i];
        for (int i = 0; i < 32; i++) lin += ntnV[t * 64 + 32 + i] * a2[i];
        z[t] = fmaxf(s + lin, 0.f);
    } else if (t < 32) {
        float tot = 0.f;
        for (int i = 0; i < BINS; i++) tot += counts[i];
        z[t] = counts[t - 16] / tot;
    }
    __syncthreads();
    if (t < 16) {
        float a = fc1b[t];
        for (int i = 0; i < 32; i++) a += fc1W[t * 32 + i] * z[i];
        u[t] = fmaxf(a, 0.f);
    }
    __syncthreads();
    if (t == 0) {
        float a = fc2b[0];
        for (int i = 0; i < 16; i++) a += fc2W[i] * u[i];
        out[b] = 1.f / (1.f + expf(-a));
    }
}

extern "C" void kernel_launch(void* const* d_in, const int* in_sizes, int n_in,
                              void* d_out, int out_size, void* d_ws, size_t ws_size,
                              hipStream_t stream) {
    const float* xq   = (const float*)d_in[0];
    const float* xc   = (const float*)d_in[1];
    const int*   eq   = (const int*)d_in[2];
    const int*   ec   = (const int*)d_in[3];
    const float* W1   = (const float*)d_in[4];
    const float* b1   = (const float*)d_in[5];
    const float* W2   = (const float*)d_in[6];
    const float* b2   = (const float*)d_in[7];
    const float* W3   = (const float*)d_in[8];
    const float* b3   = (const float*)d_in[9];
    const float* Watt = (const float*)d_in[10];
    const float* ntnW = (const float*)d_in[11];
    const float* ntnV = (const float*)d_in[12];
    const float* ntnb = (const float*)d_in[13];
    const float* fc1W = (const float*)d_in[14];
    const float* fc1b = (const float*)d_in[15];
    const float* fc2W = (const float*)d_in[16];
    const float* fc2b = (const float*)d_in[17];
    float* out = (float*)d_out;
    float* ws  = (float*)d_ws;

    // ---- workspace layout (float indices), [2B] contiguous buffers ----
    float* O3   = ws;                           // 2*B*N*32  = 2097152
    float* e12  = O3 + 2097152;                 // 2*B*32    = 8192
    float* bmin = e12 + 8192;                   // 2048
    float* bmax = bmin + 2048;                  // 2048
    float* lohi = bmax + 2048;                  // 2
    float* cntw = lohi + 2;                     // 16
    int*   off  = (int*)(ws + 2109504);         // 2B*257 = 65792
    int*   srcs = off + 65792;                  // 2B*E = 524288
    float* wts  = (float*)(srcs + 524288);      // 524288
    float* O1   = ws + 3223872;                 // 2*B*N*128 = 8388608
    float* O2   = O1 + 8388608;                 // 2*B*N*64  = 4194304

    float* O3Q = O3;
    float* O3C = O3 + (size_t)BB * NN * 32;
    float* e1w = e12;
    float* e2w = e12 + BB * 32;

    csr_kernel<<<2 * BB, 256, 0, stream>>>(eq, ec, off, srcs, wts);

    gcn_fused<128, 128, true><<<4 * 2 * BB, 512, 0, stream>>>(
        xq, xc, W1, b1, off, srcs, wts, O1);
    gcn_fused<128, 64, true><<<2 * 2 * BB, 512, 0, stream>>>(
        O1, O1 + (size_t)BB * NN * 128, W2, b2, off, srcs, wts, O2);
    gcn_fused<64, 32, false><<<1 * 2 * BB, 512, 0, stream>>>(
        O2, O2 + (size_t)BB * NN * 64, W3, b3, off, srcs, wts, O3);

    attpool_kernel<<<2 * BB, 256, 0, stream>>>(O3, Watt, e12);

    pairdot_minmax<<<BB * 16, 256, 0, stream>>>(O3Q, O3C, bmin, bmax);
    minmax_kernel<<<1, 256, 0, stream>>>(bmin, bmax, lohi, cntw);
    pairdot_hist<<<BB * 16, 256, 0, stream>>>(O3Q, O3C, lohi, cntw);

    final_kernel<<<BB, 256, 0, stream>>>(e1w, e2w, ntnW, ntnV, ntnb, cntw,
                                         fc1W, fc1b, fc2W, fc2b, out);
}